// Round 4
// baseline (33794.531 us; speedup 1.0000x reference)
//
#include <hip/hip_runtime.h>

#define Bb 512
#define Tt 512
#define Ll 256
#define Ff 256
#define Hh 128
#define H3 384
#define NZ 8
#define XC 16
#define OC 8
#define CF 9
#define BBt 2    // batches per CDE block (256 blocks)

__device__ __forceinline__ float sigm(float x){ return 1.0f/(1.0f+expf(-x)); }
__device__ __forceinline__ float softplus_(float x){
  return fmaxf(x, 0.0f) + log1pf(expf(-fabsf(x)));
}

// ---------------- GRU (fp32 vector math, per-batch persistent block) ----------
// mode 0: zx encoder. x = [coeffs_x(16), t]; writes zx (B,T,8)
// mode 1: zy encoder. x = [y_past(8), zx(8), t]; writes final h (B,128)
__global__ __launch_bounds__(384) void gru_kernel(
    const float* __restrict__ xin, const float* __restrict__ zx_in,
    const float* __restrict__ tin,
    const float* __restrict__ wih, const float* __restrict__ whh,
    const float* __restrict__ bias, const float* __restrict__ bn,
    const float* __restrict__ zxlw, const float* __restrict__ zxlb,
    float* __restrict__ out_zx, float* __restrict__ out_h,
    int steps, int mode)
{
  const int b = blockIdx.x;
  const int j = threadIdx.x;

  float wi[17];
  #pragma unroll
  for (int c = 0; c < 17; c++) wi[c] = wih[j*17 + c];
  const float bj = bias[j];
  float4 wr[32];
  {
    const float4* p = reinterpret_cast<const float4*>(whh + j*Hh);
    #pragma unroll
    for (int q = 0; q < 32; q++) wr[q] = p[q];
  }

  __shared__ __align__(16) float s_h[Hh];
  __shared__ float s_i[H3];
  __shared__ float s_g[H3];
  __shared__ float s_x[17];
  __shared__ float s_bn[Hh];
  __shared__ float s_zxlw[NZ*Hh];
  __shared__ float s_red[NZ][17];

  if (j < Hh){ s_h[j] = 0.0f; s_bn[j] = bn[j]; }
  if (mode == 0){ for (int q = j; q < NZ*Hh; q += 384) s_zxlw[q] = zxlw[q]; }
  __syncthreads();

  for (int t = 0; t < steps; t++){
    if (mode == 0){
      if (j < 16) s_x[j] = xin[(size_t)b*Tt*XC + (size_t)t*XC + j];
      else if (j == 16) s_x[16] = tin[t];
    } else {
      if (j < 8) s_x[j] = xin[(size_t)b*Ll*NZ + (size_t)t*NZ + j];
      else if (j < 16) s_x[j] = zx_in[(size_t)b*Tt*NZ + (size_t)t*NZ + (j - 8)];
      else if (j == 16) s_x[16] = tin[t];
    }
    __syncthreads();
    float ai = bj;
    #pragma unroll
    for (int c = 0; c < 17; c++) ai += wi[c]*s_x[c];
    float g0=0.f, g1=0.f, g2=0.f, g3=0.f;
    #pragma unroll
    for (int q = 0; q < 32; q++){
      float4 w = wr[q];
      float4 h4 = *reinterpret_cast<const float4*>(&s_h[q*4]);
      g0 += w.x*h4.x; g1 += w.y*h4.y; g2 += w.z*h4.z; g3 += w.w*h4.w;
    }
    s_i[j] = ai; s_g[j] = (g0+g1)+(g2+g3);
    __syncthreads();
    if (j < Hh){
      float r  = sigm(s_i[j]       + s_g[j]);
      float zz = sigm(s_i[Hh + j]  + s_g[Hh + j]);
      float n  = tanhf(s_i[2*Hh+j] + r*(s_g[2*Hh+j] + s_bn[j]));
      s_h[j] = n + zz*(s_h[j] - n);
    }
    __syncthreads();
    if (mode == 0){
      if (j < Hh){
        int o = j >> 4, m = j & 15;
        float p = 0.f;
        #pragma unroll
        for (int q = 0; q < 8; q++) p += s_zxlw[o*Hh + m*8 + q]*s_h[m*8 + q];
        s_red[o][m] = p;
      }
      __syncthreads();
      if (j < NZ){
        float p = zxlb[j];
        #pragma unroll
        for (int m = 0; m < 16; m++) p += s_red[j][m];
        out_zx[(size_t)b*Tt*NZ + (size_t)t*NZ + j] = p;
      }
      __syncthreads();
    }
  }
  if (mode == 1 && j < Hh) out_h[b*Hh + j] = s_h[j];
}

// ---------------- CDE RK4 — PURE FP32 VALU, weights register-resident ---------
// 256 blocks x 2 batches x 512 threads (8 waves). Wave wv owns:
//   G1/G2: output col n12 = 16*wv + l15 (lane holds k-quarter lg of w row)
//   G3   : cols n = 144*wv + 16*tt + l15, tt=0..8 (w3r: 9x32 fp32 = 288 VGPR)
// Partial 32-FMA dots reduced over lg via shfl_xor(16,32).
__global__ __launch_bounds__(512, 1) void cde_fp32_kernel(
    const float* __restrict__ zy_h, const float* __restrict__ zx,
    const float* __restrict__ tin,
    const float* __restrict__ fw1, const float* __restrict__ fb1,
    const float* __restrict__ fw2, const float* __restrict__ fb2,
    const float* __restrict__ fw3, const float* __restrict__ fb3,
    const float* __restrict__ rw,  const float* __restrict__ rb,
    float* __restrict__ yout)
{
  const int tid = threadIdx.x;
  const int wv = tid >> 6, lane = tid & 63, l15 = lane & 15, lg = lane >> 4;
  const int bg = blockIdx.x * BBt;

  __shared__ float s_zin[BBt][Hh];
  __shared__ float s_h1[BBt][Hh];
  __shared__ float s_h2[BBt][Hh];
  __shared__ float s_o[BBt][Hh*CF];
  __shared__ float s_z[BBt][Hh];
  __shared__ float s_kacc[BBt][Hh];
  __shared__ float s_dx[BBt][CF];
  __shared__ float s_rw[OC*Hh];
  __shared__ float s_rb[OC];

  // ---- fp32 weights into registers (static indexing only -> no scratch) ----
  const int n12 = 16*wv + l15;
  float w1r[32], w2r[32];
  {
    const float4* p1 = reinterpret_cast<const float4*>(fw1 + (size_t)n12*Hh + lg*32);
    const float4* p2 = reinterpret_cast<const float4*>(fw2 + (size_t)n12*Hh + lg*32);
    #pragma unroll
    for (int q = 0; q < 8; q++){
      float4 a = p1[q]; float4 b = p2[q];
      w1r[q*4+0]=a.x; w1r[q*4+1]=a.y; w1r[q*4+2]=a.z; w1r[q*4+3]=a.w;
      w2r[q*4+0]=b.x; w2r[q*4+1]=b.y; w2r[q*4+2]=b.z; w2r[q*4+3]=b.w;
    }
  }
  const float b1r = fb1[n12], b2r = fb2[n12];
  float w3r[9][32]; float b3r[9];
  #pragma unroll
  for (int tt = 0; tt < 9; tt++){
    const int n = 144*wv + 16*tt + l15;
    b3r[tt] = fb3[n];
    const float4* p3 = reinterpret_cast<const float4*>(fw3 + (size_t)n*Hh + lg*32);
    #pragma unroll
    for (int q = 0; q < 8; q++){
      float4 a = p3[q];
      w3r[tt][q*4+0]=a.x; w3r[tt][q*4+1]=a.y; w3r[tt][q*4+2]=a.z; w3r[tt][q*4+3]=a.w;
    }
  }

  for (int idx = tid; idx < OC*Hh; idx += 512) s_rw[idx] = rw[idx];
  if (tid < OC) s_rb[tid] = rb[tid];
  if (tid < BBt*Hh){
    int b = tid >> 7, h = tid & 127;
    float zv = zy_h[(size_t)(bg + b)*Hh + h];
    s_z[b][h] = zv;
    s_zin[b][h] = zv;
  }
  __syncthreads();

  // y[:, 0, :]
  if (tid < BBt*OC){
    int b = tid >> 3, o = tid & 7;
    float acc = s_rb[o];
    for (int h = 0; h < Hh; h++) acc += s_z[b][h]*s_rw[o*Hh + h];
    yout[(size_t)(bg + b)*Ff*OC + o] = acc;
  }

  for (int i = 0; i < Ff - 1; i++){
    // dX = [diff(zx_future), dt]
    if (tid < BBt*CF){
      int b = tid/CF, c = tid%CF;
      float d;
      if (c < 8){
        const float* zp = zx + (size_t)(bg + b)*Tt*NZ + (size_t)(Ll + i)*NZ + c;
        d = zp[NZ] - zp[0];
      } else {
        d = tin[Ll + i + 1] - tin[Ll + i];
      }
      s_dx[b][c] = d;
    }
    __syncthreads();

    for (int st = 0; st < 4; st++){
      // ---- G1: h1 = softplus(zin @ w1.T + b1) ----
      #pragma unroll
      for (int b = 0; b < BBt; b++){
        float p = 0.f;
        #pragma unroll
        for (int q = 0; q < 32; q++) p += w1r[q]*s_zin[b][lg*32 + q];
        p += __shfl_xor(p, 16, 64);
        p += __shfl_xor(p, 32, 64);
        if (lg == 0) s_h1[b][n12] = softplus_(b1r + p);
      }
      __syncthreads();
      // ---- G2: h2 = softplus(h1 @ w2.T + b2) ----
      #pragma unroll
      for (int b = 0; b < BBt; b++){
        float p = 0.f;
        #pragma unroll
        for (int q = 0; q < 32; q++) p += w2r[q]*s_h1[b][lg*32 + q];
        p += __shfl_xor(p, 16, 64);
        p += __shfl_xor(p, 32, 64);
        if (lg == 0) s_h2[b][n12] = softplus_(b2r + p);
      }
      __syncthreads();
      // ---- G3: o = tanh(h2 @ w3.T + b3) ----
      #pragma unroll
      for (int tt = 0; tt < 9; tt++){
        #pragma unroll
        for (int b = 0; b < BBt; b++){
          float p = 0.f;
          #pragma unroll
          for (int q = 0; q < 32; q++) p += w3r[tt][q]*s_h2[b][lg*32 + q];
          p += __shfl_xor(p, 16, 64);
          p += __shfl_xor(p, 32, 64);
          if (lg == 0) s_o[b][144*wv + 16*tt + l15] = tanhf(b3r[tt] + p);
        }
      }
      __syncthreads();
      // ---- einsum k = o . dx  +  RK4 combine ----
      if (tid < BBt*Hh){
        int b = tid >> 7, h = tid & 127;
        float kc = 0.f;
        #pragma unroll
        for (int c = 0; c < CF; c++) kc += s_o[b][h*CF + c]*s_dx[b][c];
        float zv = s_z[b][h], zin;
        if      (st == 0){ s_kacc[b][h] = kc;        zin = zv + 0.5f*kc; }
        else if (st == 1){ s_kacc[b][h] += 2.f*kc;   zin = zv + 0.5f*kc; }
        else if (st == 2){ s_kacc[b][h] += 2.f*kc;   zin = zv + kc; }
        else { float zn = zv + (s_kacc[b][h] + kc)*(1.f/6.f); s_z[b][h] = zn; zin = zn; }
        s_zin[b][h] = zin;
      }
      __syncthreads();
    }
    // readout y[:, i+1, :]
    if (tid < BBt*OC){
      int b = tid >> 3, o = tid & 7;
      float acc = s_rb[o];
      for (int h = 0; h < Hh; h++) acc += s_z[b][h]*s_rw[o*Hh + h];
      yout[(size_t)(bg + b)*Ff*OC + (size_t)(i + 1)*OC + o] = acc;
    }
  }
}

extern "C" void kernel_launch(void* const* d_in, const int* in_sizes, int n_in,
                              void* d_out, int out_size, void* d_ws, size_t ws_size,
                              hipStream_t stream)
{
  (void)in_sizes; (void)n_in; (void)out_size; (void)ws_size;
  const float* y_past = (const float*)d_in[0];
  const float* t_in   = (const float*)d_in[1];
  const float* coeffs = (const float*)d_in[2];
  // d_in[3] = input_length (fixed 256)
  const float* zx_wih = (const float*)d_in[4];
  const float* zx_whh = (const float*)d_in[5];
  const float* zx_b   = (const float*)d_in[6];
  const float* zx_bn  = (const float*)d_in[7];
  const float* zxl_w  = (const float*)d_in[8];
  const float* zxl_b  = (const float*)d_in[9];
  const float* zy_wih = (const float*)d_in[10];
  const float* zy_whh = (const float*)d_in[11];
  const float* zy_b   = (const float*)d_in[12];
  const float* zy_bn  = (const float*)d_in[13];
  const float* fw1 = (const float*)d_in[14];
  const float* fb1 = (const float*)d_in[15];
  const float* fw2 = (const float*)d_in[16];
  const float* fb2 = (const float*)d_in[17];
  const float* fw3 = (const float*)d_in[18];
  const float* fb3 = (const float*)d_in[19];
  const float* r_w = (const float*)d_in[20];
  const float* r_b = (const float*)d_in[21];

  float* ws = (float*)d_ws;
  float* zx_buf = ws;                              // B*T*NZ fp32 = 8.39 MB
  float* zy_buf = ws + (size_t)Bb*Tt*NZ;           // B*H fp32   = 256 KB

  gru_kernel<<<Bb, 384, 0, stream>>>(coeffs, nullptr, t_in,
                                     zx_wih, zx_whh, zx_b, zx_bn,
                                     zxl_w, zxl_b, zx_buf, nullptr, Tt, 0);
  gru_kernel<<<Bb, 384, 0, stream>>>(y_past, zx_buf, t_in,
                                     zy_wih, zy_whh, zy_b, zy_bn,
                                     nullptr, nullptr, nullptr, zy_buf, Ll, 1);
  cde_fp32_kernel<<<Bb/BBt, 512, 0, stream>>>(zy_buf, zx_buf, t_in,
                                              fw1, fb1, fw2, fb2, fw3, fb3,
                                              r_w, r_b, (float*)d_out);
}

// Round 5
// 26571.484 us; speedup vs baseline: 1.2718x; 1.2718x over previous
//
#include <hip/hip_runtime.h>

#define Bb 512
#define Tt 512
#define Ll 256
#define Ff 256
#define Hh 128
#define H3 384
#define NZ 8
#define XC 16
#define OC 8
#define CF 9
#define BBt 2    // batches per CDE block (256 blocks)

__device__ __forceinline__ float sigm(float x){ return 1.0f/(1.0f+expf(-x)); }
__device__ __forceinline__ float softplus_(float x){
  return fmaxf(x, 0.0f) + log1pf(expf(-fabsf(x)));
}
__device__ __forceinline__ float dot16(const float4* w, const float4* z){
  float p = 0.f;
  #pragma unroll
  for (int j = 0; j < 4; j++){
    p += w[j].x*z[j].x; p += w[j].y*z[j].y;
    p += w[j].z*z[j].z; p += w[j].w*z[j].w;
  }
  return p;
}
__device__ __forceinline__ float bf8sum(float p){   // sum over k-eighth groups (lane bits 3..5)
  p += __shfl_xor(p, 8, 64);
  p += __shfl_xor(p, 16, 64);
  p += __shfl_xor(p, 32, 64);
  return p;
}

// ---------------- GRU (fp32 vector math, per-batch persistent block) ----------
// mode 0: zx encoder. x = [coeffs_x(16), t]; writes zx (B,T,8)
// mode 1: zy encoder. x = [y_past(8), zx(8), t]; writes final h (B,128)
__global__ __launch_bounds__(384) void gru_kernel(
    const float* __restrict__ xin, const float* __restrict__ zx_in,
    const float* __restrict__ tin,
    const float* __restrict__ wih, const float* __restrict__ whh,
    const float* __restrict__ bias, const float* __restrict__ bn,
    const float* __restrict__ zxlw, const float* __restrict__ zxlb,
    float* __restrict__ out_zx, float* __restrict__ out_h,
    int steps, int mode)
{
  const int b = blockIdx.x;
  const int j = threadIdx.x;

  float wi[17];
  #pragma unroll
  for (int c = 0; c < 17; c++) wi[c] = wih[j*17 + c];
  const float bj = bias[j];
  float4 wr[32];
  {
    const float4* p = reinterpret_cast<const float4*>(whh + j*Hh);
    #pragma unroll
    for (int q = 0; q < 32; q++) wr[q] = p[q];
  }

  __shared__ __align__(16) float s_h[Hh];
  __shared__ float s_i[H3];
  __shared__ float s_g[H3];
  __shared__ float s_x[17];
  __shared__ float s_bn[Hh];
  __shared__ float s_zxlw[NZ*Hh];
  __shared__ float s_red[NZ][17];

  if (j < Hh){ s_h[j] = 0.0f; s_bn[j] = bn[j]; }
  if (mode == 0){ for (int q = j; q < NZ*Hh; q += 384) s_zxlw[q] = zxlw[q]; }
  __syncthreads();

  for (int t = 0; t < steps; t++){
    if (mode == 0){
      if (j < 16) s_x[j] = xin[(size_t)b*Tt*XC + (size_t)t*XC + j];
      else if (j == 16) s_x[16] = tin[t];
    } else {
      if (j < 8) s_x[j] = xin[(size_t)b*Ll*NZ + (size_t)t*NZ + j];
      else if (j < 16) s_x[j] = zx_in[(size_t)b*Tt*NZ + (size_t)t*NZ + (j - 8)];
      else if (j == 16) s_x[16] = tin[t];
    }
    __syncthreads();
    float ai = bj;
    #pragma unroll
    for (int c = 0; c < 17; c++) ai += wi[c]*s_x[c];
    float g0=0.f, g1=0.f, g2=0.f, g3=0.f;
    #pragma unroll
    for (int q = 0; q < 32; q++){
      float4 w = wr[q];
      float4 h4 = *reinterpret_cast<const float4*>(&s_h[q*4]);
      g0 += w.x*h4.x; g1 += w.y*h4.y; g2 += w.z*h4.z; g3 += w.w*h4.w;
    }
    s_i[j] = ai; s_g[j] = (g0+g1)+(g2+g3);
    __syncthreads();
    if (j < Hh){
      float r  = sigm(s_i[j]       + s_g[j]);
      float zz = sigm(s_i[Hh + j]  + s_g[Hh + j]);
      float n  = tanhf(s_i[2*Hh+j] + r*(s_g[2*Hh+j] + s_bn[j]));
      s_h[j] = n + zz*(s_h[j] - n);
    }
    __syncthreads();
    if (mode == 0){
      if (j < Hh){
        int o = j >> 4, m = j & 15;
        float p = 0.f;
        #pragma unroll
        for (int q = 0; q < 8; q++) p += s_zxlw[o*Hh + m*8 + q]*s_h[m*8 + q];
        s_red[o][m] = p;
      }
      __syncthreads();
      if (j < NZ){
        float p = zxlb[j];
        #pragma unroll
        for (int m = 0; m < 16; m++) p += s_red[j][m];
        out_zx[(size_t)b*Tt*NZ + (size_t)t*NZ + j] = p;
      }
      __syncthreads();
    }
  }
  if (mode == 1 && j < Hh) out_h[b*Hh + j] = s_h[j];
}

// ---------------- CDE RK4 — FP32 VALU, 16 waves, small per-lane weight sets ----
// 256 blocks x 2 batches x 1024 threads (16 waves). Wave wv owns:
//   G1/G2: cols 8wv..8wv+7  (lane: col=8wv+l7, k-eighth g) -> w1q/w2q = 16 fp32
//   G3   : cols 72wv..72wv+71 as 9 tiles of 8 cols         -> w3q = 144 fp32
// 16-FMA partial dots reduced over g via shfl_xor(8,16,32).
__global__ __launch_bounds__(1024, 4) void cde_fp32_kernel(
    const float* __restrict__ zy_h, const float* __restrict__ zx,
    const float* __restrict__ tin,
    const float* __restrict__ fw1, const float* __restrict__ fb1,
    const float* __restrict__ fw2, const float* __restrict__ fb2,
    const float* __restrict__ fw3, const float* __restrict__ fb3,
    const float* __restrict__ rw,  const float* __restrict__ rb,
    float* __restrict__ yout)
{
  const int tid = threadIdx.x;
  const int wv = tid >> 6, lane = tid & 63;
  const int l7 = lane & 7, g = lane >> 3;
  const int bg = blockIdx.x * BBt;

  __shared__ __align__(16) float s_zin[BBt][Hh];
  __shared__ __align__(16) float s_h1[BBt][Hh];
  __shared__ __align__(16) float s_h2[BBt][Hh];
  __shared__ float s_o[BBt][Hh*CF];
  __shared__ float s_z[BBt][Hh];
  __shared__ float s_kacc[BBt][Hh];
  __shared__ float s_dx[BBt][CF];
  __shared__ float s_rw[OC*Hh];
  __shared__ float s_rb[OC];

  // ---- fp32 weights -> registers (small per-lane sets, static indexing) ----
  const int c12 = 8*wv + l7;
  float4 w1q[4], w2q[4];
  {
    const float4* p1 = reinterpret_cast<const float4*>(fw1 + (size_t)c12*Hh + g*16);
    const float4* p2 = reinterpret_cast<const float4*>(fw2 + (size_t)c12*Hh + g*16);
    #pragma unroll
    for (int j = 0; j < 4; j++){ w1q[j] = p1[j]; w2q[j] = p2[j]; }
  }
  const float b1r = fb1[c12], b2r = fb2[c12];
  float4 w3q[9][4]; float b3r[9];
  #pragma unroll
  for (int tt = 0; tt < 9; tt++){
    const int n = 72*wv + 8*tt + l7;
    b3r[tt] = fb3[n];
    const float4* p3 = reinterpret_cast<const float4*>(fw3 + (size_t)n*Hh + g*16);
    #pragma unroll
    for (int j = 0; j < 4; j++) w3q[tt][j] = p3[j];
  }

  if (tid < OC*Hh) s_rw[tid] = rw[tid];
  if (tid < OC) s_rb[tid] = rb[tid];
  if (tid < BBt*Hh){
    int b = tid >> 7, h = tid & 127;
    float zv = zy_h[(size_t)(bg + b)*Hh + h];
    s_z[b][h] = zv;
    s_zin[b][h] = zv;
  }
  __syncthreads();

  // y[:, 0, :] via 16-lane shfl-reduced dots
  if (tid < 256){
    int b = tid >> 7, r = tid & 127, o = r >> 4, seg = r & 15;
    float p = 0.f;
    #pragma unroll
    for (int q = 0; q < 8; q++)
      p += s_z[b][seg*8 + q]*s_rw[o*Hh + seg*8 + q];
    p += __shfl_xor(p, 1, 64); p += __shfl_xor(p, 2, 64);
    p += __shfl_xor(p, 4, 64); p += __shfl_xor(p, 8, 64);
    if (seg == 0) yout[(size_t)(bg + b)*Ff*OC + o] = s_rb[o] + p;
  }

  for (int i = 0; i < Ff - 1; i++){
    // dX = [diff(zx_future), dt]
    if (tid < BBt*CF){
      int b = tid/CF, c = tid%CF;
      float d;
      if (c < 8){
        const float* zp = zx + (size_t)(bg + b)*Tt*NZ + (size_t)(Ll + i)*NZ + c;
        d = zp[NZ] - zp[0];
      } else {
        d = tin[Ll + i + 1] - tin[Ll + i];
      }
      s_dx[b][c] = d;
    }
    __syncthreads();

    for (int st = 0; st < 4; st++){
      // ---- G1: h1 = softplus(zin @ w1.T + b1) ----
      {
        float p[BBt];
        #pragma unroll
        for (int b = 0; b < BBt; b++){
          float4 z[4];
          const float4* zp = reinterpret_cast<const float4*>(&s_zin[b][g*16]);
          #pragma unroll
          for (int j = 0; j < 4; j++) z[j] = zp[j];
          p[b] = bf8sum(dot16(w1q, z));
        }
        if (lane < 8){
          #pragma unroll
          for (int b = 0; b < BBt; b++)
            s_h1[b][c12] = softplus_(b1r + p[b]);
        }
      }
      __syncthreads();
      // ---- G2: h2 = softplus(h1 @ w2.T + b2) ----
      {
        float p[BBt];
        #pragma unroll
        for (int b = 0; b < BBt; b++){
          float4 z[4];
          const float4* zp = reinterpret_cast<const float4*>(&s_h1[b][g*16]);
          #pragma unroll
          for (int j = 0; j < 4; j++) z[j] = zp[j];
          p[b] = bf8sum(dot16(w2q, z));
        }
        if (lane < 8){
          #pragma unroll
          for (int b = 0; b < BBt; b++)
            s_h2[b][c12] = softplus_(b2r + p[b]);
        }
      }
      __syncthreads();
      // ---- G3 raw: s_o = h2 @ w3.T + b3 (tanh deferred to phase A) ----
      {
        float4 z0[4], z1[4];
        {
          const float4* zp0 = reinterpret_cast<const float4*>(&s_h2[0][g*16]);
          const float4* zp1 = reinterpret_cast<const float4*>(&s_h2[1][g*16]);
          #pragma unroll
          for (int j = 0; j < 4; j++){ z0[j] = zp0[j]; z1[j] = zp1[j]; }
        }
        #pragma unroll
        for (int tt = 0; tt < 9; tt++){
          float p0 = bf8sum(dot16(w3q[tt], z0));
          float p1 = bf8sum(dot16(w3q[tt], z1));
          if (lane < 8){
            int n = 72*wv + 8*tt + lane;
            s_o[0][n] = b3r[tt] + p0;
            s_o[1][n] = b3r[tt] + p1;
          }
        }
      }
      __syncthreads();
      // ---- phase A: o <- tanh(o) * dx[c], spread over all 1024 threads ----
      for (int v = tid; v < BBt*Hh*CF; v += 1024){
        int b = v / (Hh*CF), n = v - b*(Hh*CF);
        s_o[b][n] = tanhf(s_o[b][n]) * s_dx[b][n % CF];
      }
      __syncthreads();
      // ---- phase B: k_h = sum_c o*dx  +  RK4 combine ----
      if (tid < BBt*Hh){
        int b = tid >> 7, h = tid & 127;
        float kc = 0.f;
        #pragma unroll
        for (int c = 0; c < CF; c++) kc += s_o[b][h*CF + c];
        float zv = s_z[b][h], zin;
        if      (st == 0){ s_kacc[b][h] = kc;        zin = zv + 0.5f*kc; }
        else if (st == 1){ s_kacc[b][h] += 2.f*kc;   zin = zv + 0.5f*kc; }
        else if (st == 2){ s_kacc[b][h] += 2.f*kc;   zin = zv + kc; }
        else { float zn = zv + (s_kacc[b][h] + kc)*(1.f/6.f); s_z[b][h] = zn; zin = zn; }
        s_zin[b][h] = zin;
      }
      __syncthreads();
    }
    // readout y[:, i+1, :]
    if (tid < 256){
      int b = tid >> 7, r = tid & 127, o = r >> 4, seg = r & 15;
      float p = 0.f;
      #pragma unroll
      for (int q = 0; q < 8; q++)
        p += s_z[b][seg*8 + q]*s_rw[o*Hh + seg*8 + q];
      p += __shfl_xor(p, 1, 64); p += __shfl_xor(p, 2, 64);
      p += __shfl_xor(p, 4, 64); p += __shfl_xor(p, 8, 64);
      if (seg == 0) yout[(size_t)(bg + b)*Ff*OC + (size_t)(i + 1)*OC + o] = s_rb[o] + p;
    }
  }
}

extern "C" void kernel_launch(void* const* d_in, const int* in_sizes, int n_in,
                              void* d_out, int out_size, void* d_ws, size_t ws_size,
                              hipStream_t stream)
{
  (void)in_sizes; (void)n_in; (void)out_size; (void)ws_size;
  const float* y_past = (const float*)d_in[0];
  const float* t_in   = (const float*)d_in[1];
  const float* coeffs = (const float*)d_in[2];
  // d_in[3] = input_length (fixed 256)
  const float* zx_wih = (const float*)d_in[4];
  const float* zx_whh = (const float*)d_in[5];
  const float* zx_b   = (const float*)d_in[6];
  const float* zx_bn  = (const float*)d_in[7];
  const float* zxl_w  = (const float*)d_in[8];
  const float* zxl_b  = (const float*)d_in[9];
  const float* zy_wih = (const float*)d_in[10];
  const float* zy_whh = (const float*)d_in[11];
  const float* zy_b   = (const float*)d_in[12];
  const float* zy_bn  = (const float*)d_in[13];
  const float* fw1 = (const float*)d_in[14];
  const float* fb1 = (const float*)d_in[15];
  const float* fw2 = (const float*)d_in[16];
  const float* fb2 = (const float*)d_in[17];
  const float* fw3 = (const float*)d_in[18];
  const float* fb3 = (const float*)d_in[19];
  const float* r_w = (const float*)d_in[20];
  const float* r_b = (const float*)d_in[21];

  float* ws = (float*)d_ws;
  float* zx_buf = ws;                              // B*T*NZ fp32 = 8.39 MB
  float* zy_buf = ws + (size_t)Bb*Tt*NZ;           // B*H fp32   = 256 KB

  gru_kernel<<<Bb, 384, 0, stream>>>(coeffs, nullptr, t_in,
                                     zx_wih, zx_whh, zx_b, zx_bn,
                                     zxl_w, zxl_b, zx_buf, nullptr, Tt, 0);
  gru_kernel<<<Bb, 384, 0, stream>>>(y_past, zx_buf, t_in,
                                     zy_wih, zy_whh, zy_b, zy_bn,
                                     nullptr, nullptr, nullptr, zy_buf, Ll, 1);
  cde_fp32_kernel<<<Bb/BBt, 1024, 0, stream>>>(zy_buf, zx_buf, t_in,
                                               fw1, fb1, fw2, fb2, fw3, fb3,
                                               r_w, r_b, (float*)d_out);
}